// Round 4
// baseline (137.446 us; speedup 1.0000x reference)
//
#include <hip/hip_runtime.h>

// Problem constants (from setup_inputs): B=32, S=524288, HOP=256, L=100.
constexpr int HOP    = 256;
constexpr int L      = 100;
constexpr int FRAMES = 2048;   // S / HOP
constexpr int B      = 32;
constexpr int FPW    = 8;      // frames per wave
constexpr int TOTF   = B * FRAMES;        // 65536 frames
constexpr int NWAVE  = TOTF / FPW;        // 8192 waves
constexpr int NBLK   = NWAVE / 4;         // 2048 blocks (256 thr) = 8/CU, 32 waves/CU

// Barrier-free streaming: each wave is an independent pipeline over its own
// private LDS slice (no cross-wave LDS sharing -> zero __syncthreads -> no
// block-wide vmcnt(0) drain -> continuous, unaligned memory demand across the
// 32 resident waves per CU). Per frame: stage this wave's 2 table rows
// (800 B, contiguous in memory) into the private double buffer, prefetching
// the next frame's rows + wp under the current frame's compute.
__global__ __launch_bounds__(256) void glottal_kernel(
    const float* __restrict__ wp,
    const float* __restrict__ tables,
    float* __restrict__ out)
{
    // [wave][buf][200 dwords]: floor row at [0..99], ceil row at [100..199].
    __shared__ float priv[4][2][2 * L];   // 6400 B per block

    const int tid  = threadIdx.x;
    const int wv   = tid >> 6;
    const int lane = tid & 63;
    const int f0   = (blockIdx.x * 4 + wv) * FPW;   // first frame of this wave

    float (*pv)[2 * L] = priv[wv];

    // Rows f and f+1 are contiguous: one 800 B segment = lanes 0..49 x 16 B.
    auto row_ptr = [&](int f) {
        const int b = f >> 11;            // / FRAMES
        const int r = f & (FRAMES - 1);
        return tables + ((size_t)b * (FRAMES + 1) + (size_t)r) * L;
    };

    // ---- Prologue: stage frame f0.
    float4 rcur = make_float4(0.f, 0.f, 0.f, 0.f);
    if (lane < 50)
        rcur = *reinterpret_cast<const float4*>(row_ptr(f0) + lane * 4);
    float4 wcur = *reinterpret_cast<const float4*>(wp + (size_t)f0 * HOP + lane * 4);
    if (lane < 50)
        *reinterpret_cast<float4*>(&pv[0][lane * 4]) = rcur;

    float4 rnxt, wnxt;
    for (int it = 0; it < FPW; ++it) {
        const int f  = f0 + it;
        const int pp = it & 1;

        // Issue next frame's loads first (latency hides under this compute).
        if (it + 1 < FPW) {
            if (lane < 50)
                rnxt = *reinterpret_cast<const float4*>(row_ptr(f + 1) + lane * 4);
            wnxt = *reinterpret_cast<const float4*>(wp + (size_t)(f + 1) * HOP + lane * 4);
        }

        // ---- Compute frame f from private LDS (ds_read2_b32-shaped gathers).
        const float* t = pv[pp];
        const float  wv4[4] = {wcur.x, wcur.y, wcur.z, wcur.w};
        float res[4];
#pragma unroll
        for (int k = 0; k < 4; ++k) {
            const float ir = wv4[k] * (float)L;
            int fi = (int)ir;                      // trunc; wp >= 0
            fi = fi > L - 1 ? L - 1 : fi;          // reference clip
            const float p   = ir - (float)fi;
            const int   ihi = (fi + 1 == L) ? 0 : fi + 1;   // padded wrap column
            const float lo0 = t[fi],       cl0 = t[fi + L];
            const float lo1 = t[ihi],      cl1 = t[ihi + L];
            const float sf  = lo0 + (lo1 - lo0) * p;   // sel_floor
            const float sc  = cl0 + (cl1 - cl0) * p;   // sel_ceil
            const float p2  = (float)(lane * 4 + k) * (1.0f / HOP);
            res[k] = sf + (sc - sf) * p2;
        }

        *reinterpret_cast<float4*>(out + (size_t)f * HOP + lane * 4) =
            make_float4(res[0], res[1], res[2], res[3]);

        // ---- Retire prefetch into the other private buffer (wave-local
        // ordering only: vmcnt for rnxt, lgkmcnt orders ds_write vs next reads).
        if (it + 1 < FPW) {
            if (lane < 50)
                *reinterpret_cast<float4*>(&pv[pp ^ 1][lane * 4]) = rnxt;
            wcur = wnxt;
        }
    }
}

extern "C" void kernel_launch(void* const* d_in, const int* in_sizes, int n_in,
                              void* d_out, int out_size, void* d_ws, size_t ws_size,
                              hipStream_t stream) {
    const float* wp     = (const float*)d_in[0];
    const float* tables = (const float*)d_in[1];
    // d_in[2] is hop_length (scalar int) — baked in as constexpr HOP.
    float* out = (float*)d_out;

    dim3 grid(NBLK);   // 2048 blocks, 4 independent waves each
    glottal_kernel<<<grid, 256, 0, stream>>>(wp, tables, out);
}